// Round 4
// baseline (1745.348 us; speedup 1.0000x reference)
//
#include <hip/hip_runtime.h>
#include <hip/hip_bf16.h>
#include <stdint.h>

typedef __attribute__((ext_vector_type(8))) short short8;
typedef __attribute__((ext_vector_type(4))) float f32x4;

#define N_DRUG 708
#define N_TGT  1512
#define N_NODES 7823
#define N_D_T  2220          // 708+1512
#define KPAD   7936          // 124 * 64
#define NROWP  7872          // 123 * 64 (padded rows of adjb)
#define NTOT   2002688       // 7823*256
#define NSPLIT 8

__device__ __forceinline__ unsigned short f2bf(float f) {
  union { float f; unsigned int i; } v; v.f = f;
  unsigned int r = v.i + 0x7FFF + ((v.i >> 16) & 1);
  return (unsigned short)(r >> 16);
}

__device__ __forceinline__ int4 pack8(const float v[8]) {
  union { int4 i4; unsigned short u[8]; } r;
  #pragma unroll
  for (int j = 0; j < 8; j++) r.u[j] = f2bf(v[j]);
  return r.i4;
}

// ---------------------------------------------------------------- cast kernels

__global__ __launch_bounds__(256) void cast_wc(
    const float* __restrict__ w0, const float* __restrict__ wr0,
    const float* __restrict__ w1, const float* __restrict__ wr1,
    const float* __restrict__ w2, const float* __restrict__ wr2,
    unsigned short* __restrict__ Wc)
{
  long long i4 = ((long long)blockIdx.x*256 + threadIdx.x)*4;   // over 3*1024*1024
  int g  = (int)(i4 >> 20);
  int rr = (int)((i4 >> 10) & 1023);
  int c  = (int)(i4 & 1023);
  const float* src = (g==0) ? (rr<512?w0:wr0) : (g==1) ? (rr<512?w1:wr1) : (rr<512?w2:wr2);
  float4 f = *(const float4*)(src + (long long)(rr & 511)*1024 + c);
  ushort4 v; v.x=f2bf(f.x); v.y=f2bf(f.y); v.z=f2bf(f.z); v.w=f2bf(f.w);
  *(ushort4*)&Wc[i4] = v;
}

__global__ __launch_bounds__(256) void transpose_cast(
    const float* __restrict__ src, unsigned short* __restrict__ dst, int R, int C)
{
  int i = blockIdx.x*256 + threadIdx.x;
  if (i >= R*C) return;
  int r = i / C, c = i - r*C;
  dst[c*R + r] = f2bf(src[i]);
}

// ---------------------------------------------------------------- templated GEMM
// C[m][n] = sum_k A[m][k] * BT[n][k].  BM x 256 tile, BK=64, 512 thr, 8 waves (2x4),
// XOR-swizzled LDS, register prefetch of next K-tile.
// AMODE 0: A bf16 (Ab, lda)
// AMODE 1: A f32 cast-in-flight (Af, lda)
// AMODE 2: A = mean of two f32 planes (Af, Af+plane_stride), cast, AND side-write
//          bf16 result to sideW[row][k] (row unclamped, ldsw). k >= k_cnt -> 0.
// mode 0: f32 row-major store to Cf + ks*part_stride (rows < m_cnt)
// mode 1: bf16 transposed store CT[n][m], zero-fill m >= m_cnt

#define BN 256
#define BK 64

template<int BM_, int AMODE>
__global__ __launch_bounds__(512, 8) void gemmT(
    const unsigned short* __restrict__ Ab, const float* __restrict__ Af,
    long long plane_stride, int lda, int k_cnt,
    const unsigned short* __restrict__ BT, int ldb,
    unsigned short* __restrict__ sideW, int ldsw,
    int m_cnt, int tiles_m, int tiles_n, int ksplit, int ktiles,
    int mode, float* __restrict__ Cf, int ldc, long long part_stride,
    unsigned short* __restrict__ CT, int ldct)
{
  constexpr int ACH = BM_/64;      // A chunks per thread
  constexpr int MF  = BM_/32;      // m fragments per wave
  __shared__ __align__(16) unsigned short As[BM_*BK];
  __shared__ __align__(16) unsigned short Bs[BN*BK];

  int bid = blockIdx.x;
  int tn = bid % tiles_n;
  int tm = (bid / tiles_n) % tiles_m;
  int ks = bid / (tiles_n * tiles_m);

  int m0 = tm*BM_, n0 = tn*BN;
  int ktper = (ktiles + ksplit - 1) / ksplit;
  int kt0 = ks*ktper;
  int kt1 = min(kt0 + ktper, ktiles);

  int tid = threadIdx.x;
  int lane = tid & 63, w = tid >> 6;
  int wm = (w >> 2)*(BM_/2), wn = (w & 3)*64;

  f32x4 acc[MF][4] = {};

  int arow[ACH], aslot[ACH], brow[4], bslot[4];
  #pragma unroll
  for (int i=0;i<ACH;i++){ int c = i*512 + tid; arow[i] = c>>3; aslot[i] = c&7; }
  #pragma unroll
  for (int i=0;i<4;i++){ int c = i*512 + tid; brow[i] = c>>3; bslot[i] = c&7; }

  int4 ra[ACH], rb[4];

  auto loadAB = [&](int kt){
    #pragma unroll
    for (int i=0;i<ACH;i++){
      int gr = m0 + arow[i]; if (gr > m_cnt-1) gr = m_cnt-1;
      int cb = kt*BK + aslot[i]*8;
      if (AMODE == 0) {
        ra[i] = *(const int4*)(Ab + (long long)gr*lda + cb);
      } else if (AMODE == 1) {
        const float* p = Af + (long long)gr*lda + cb;
        float4 f0 = *(const float4*)p;
        float4 f1 = *(const float4*)(p+4);
        float v[8] = {f0.x,f0.y,f0.z,f0.w,f1.x,f1.y,f1.z,f1.w};
        ra[i] = pack8(v);
      } else {
        const float* p0 = Af + (long long)gr*lda + cb;
        const float* p1 = p0 + plane_stride;
        float v[8];
        if (cb + 8 <= k_cnt) {
          float4 a0 = *(const float4*)p0, a1 = *(const float4*)(p0+4);
          float4 c0 = *(const float4*)p1, c1 = *(const float4*)(p1+4);
          v[0]=0.5f*(a0.x+c0.x); v[1]=0.5f*(a0.y+c0.y);
          v[2]=0.5f*(a0.z+c0.z); v[3]=0.5f*(a0.w+c0.w);
          v[4]=0.5f*(a1.x+c1.x); v[5]=0.5f*(a1.y+c1.y);
          v[6]=0.5f*(a1.z+c1.z); v[7]=0.5f*(a1.w+c1.w);
        } else {
          #pragma unroll
          for (int j=0;j<8;j++){
            int c = cb + j;
            v[j] = (c < k_cnt) ? 0.5f*(p0[j] + p1[j]) : 0.f;
          }
        }
        ra[i] = pack8(v);
      }
    }
    #pragma unroll
    for (int i=0;i<4;i++){
      rb[i] = *(const int4*)(BT + (long long)(n0 + brow[i])*ldb + kt*BK + bslot[i]*8);
    }
  };
  auto storeAB = [&](int kt){
    #pragma unroll
    for (int i=0;i<ACH;i++){
      *(int4*)(As + arow[i]*BK + (aslot[i]^(arow[i]&7))*8) = ra[i];
      if (AMODE == 2) {
        int gr = m0 + arow[i];   // unclamped; padded rows written but never read
        *(int4*)(sideW + (long long)gr*ldsw + kt*BK + aslot[i]*8) = ra[i];
      }
    }
    #pragma unroll
    for (int i=0;i<4;i++)
      *(int4*)(Bs + brow[i]*BK + (bslot[i]^(brow[i]&7))*8) = rb[i];
  };

  loadAB(kt0);

  for (int kt = kt0; kt < kt1; ++kt) {
    __syncthreads();
    storeAB(kt);
    __syncthreads();
    if (kt+1 < kt1) loadAB(kt+1);
    #pragma unroll
    for (int kk=0; kk<2; ++kk) {
      short8 av[MF], bv[4];
      #pragma unroll
      for (int x=0;x<MF;x++){
        int row = wm + x*16 + (lane&15);
        int slot = kk*4 + (lane>>4);
        av[x] = *(const short8*)&As[row*BK + (slot^(row&7))*8];
      }
      #pragma unroll
      for (int x=0;x<4;x++){
        int row = wn + x*16 + (lane&15);
        int slot = kk*4 + (lane>>4);
        bv[x] = *(const short8*)&Bs[row*BK + (slot^(row&7))*8];
      }
      #pragma unroll
      for (int mf=0; mf<MF; ++mf)
        #pragma unroll
        for (int nf=0; nf<4; ++nf)
          acc[mf][nf] = __builtin_amdgcn_mfma_f32_16x16x32_bf16(av[mf], bv[nf], acc[mf][nf], 0, 0, 0);
    }
  }

  if (mode == 0) {
    float* C = Cf + (long long)ks*part_stride;
    #pragma unroll
    for (int mf=0; mf<MF; ++mf) {
      int mb = m0 + wm + mf*16 + ((lane>>4)<<2);
      #pragma unroll
      for (int i=0;i<4;i++){
        int m = mb + i;
        if (m < m_cnt) {
          #pragma unroll
          for (int nf=0; nf<4; ++nf) {
            int n = n0 + wn + nf*16 + (lane&15);
            C[(long long)m*ldc + n] = acc[mf][nf][i];
          }
        }
      }
    }
  } else {
    #pragma unroll
    for (int nf=0; nf<4; ++nf) {
      int n = n0 + wn + nf*16 + (lane&15);
      #pragma unroll
      for (int mf=0; mf<MF; ++mf) {
        int mb = m0 + wm + mf*16 + ((lane>>4)<<2);
        ushort4 v;
        v.x = (mb+0 < m_cnt) ? f2bf(acc[mf][nf][0]) : (unsigned short)0;
        v.y = (mb+1 < m_cnt) ? f2bf(acc[mf][nf][1]) : (unsigned short)0;
        v.z = (mb+2 < m_cnt) ? f2bf(acc[mf][nf][2]) : (unsigned short)0;
        v.w = (mb+3 < m_cnt) ? f2bf(acc[mf][nf][3]) : (unsigned short)0;
        *(ushort4*)&CT[(long long)n*ldct + mb] = v;
      }
    }
  }
}

// ---------------------------------------------------------------- fused epilogues

__global__ __launch_bounds__(256) void adapter_fuse(
    const float* __restrict__ C1,
    const float* __restrict__ b0, const float* __restrict__ g0, const float* __restrict__ be0, const float* __restrict__ br0,
    const float* __restrict__ b1, const float* __restrict__ g1, const float* __restrict__ be1, const float* __restrict__ br1,
    const float* __restrict__ b2, const float* __restrict__ g2, const float* __restrict__ be2, const float* __restrict__ br2,
    unsigned short* __restrict__ xall)
{
  int r = blockIdx.x;
  const float *b, *g, *be, *br;
  if (r < N_DRUG)     { b=b0; g=g0; be=be0; br=br0; }
  else if (r < N_D_T) { b=b1; g=g1; be=be1; br=br1; }
  else                { b=b2; g=g2; be=be2; br=br2; }
  int t = threadIdx.x;
  const float* row = C1 + (long long)r*1024;
  float ya = row[t]       + b[t];
  float yb = row[t + 256] + b[t + 256];
  float s = ya + yb, q = ya*ya + yb*yb;
  #pragma unroll
  for (int o=32;o;o>>=1){ s += __shfl_down(s,o); q += __shfl_down(q,o); }
  __shared__ float ss[4], qq[4];
  if ((t & 63) == 0) { ss[t>>6]=s; qq[t>>6]=q; }
  __syncthreads();
  float S = ss[0]+ss[1]+ss[2]+ss[3];
  float Q = qq[0]+qq[1]+qq[2]+qq[3];
  float mean = S * (1.f/512.f);
  float var  = Q * (1.f/512.f) - mean*mean;
  float inv  = rsqrtf(var + 1e-5f);
  float za = fmaxf((ya-mean)*inv*g[t]     + be[t],     0.f);
  float zb = fmaxf((yb-mean)*inv*g[t+256] + be[t+256], 0.f);
  float ha = za + row[512 + t] + br[t];
  float hb = zb + row[768 + t] + br[t + 256];
  ha = (ha > 0.f) ? ha : (expf(ha) - 1.f);
  hb = (hb > 0.f) ? hb : (expf(hb) - 1.f);
  xall[(long long)r*512 + t]       = f2bf(ha);
  xall[(long long)r*512 + t + 256] = f2bf(hb);
}

__global__ __launch_bounds__(256) void reduce_prelu(
    const float* __restrict__ parts, const float* __restrict__ aP, unsigned short* __restrict__ h)
{
  long long i = (long long)blockIdx.x*256 + threadIdx.x;
  float s = 0.f;
  #pragma unroll
  for (int p=0;p<NSPLIT;p++) s += parts[(long long)p*NTOT + i];
  float a = aP[0];
  h[i] = f2bf(s >= 0.f ? s : a*s);
}

__global__ __launch_bounds__(256) void reduce_stats(
    const float* __restrict__ parts, float* __restrict__ Z, float* __restrict__ sp)
{
  long long i = (long long)blockIdx.x*256 + threadIdx.x;
  float s = 0.f;
  #pragma unroll
  for (int p=0;p<NSPLIT;p++) s += parts[(long long)p*NTOT + i];
  Z[i] = s;
  float a = s, q = s*s;
  #pragma unroll
  for (int o=32;o;o>>=1){ a += __shfl_down(a,o); q += __shfl_down(q,o); }
  __shared__ float ss[4], qq[4];
  int t = threadIdx.x;
  if ((t&63)==0){ ss[t>>6]=a; qq[t>>6]=q; }
  __syncthreads();
  if (t==0) {
    sp[2*blockIdx.x]   = ss[0]+ss[1]+ss[2]+ss[3];
    sp[2*blockIdx.x+1] = qq[0]+qq[1]+qq[2]+qq[3];
  }
}

__global__ __launch_bounds__(256) void stats_final(
    const float* __restrict__ sp, float* __restrict__ stats)
{
  int t = threadIdx.x;
  float s = 0.f, q = 0.f;
  for (int i=t; i<N_NODES; i+=256){ s += sp[2*i]; q += sp[2*i+1]; }
  #pragma unroll
  for (int o=32;o;o>>=1){ s += __shfl_down(s,o); q += __shfl_down(q,o); }
  __shared__ float ss[4], qq[4];
  if ((t&63)==0){ ss[t>>6]=s; qq[t>>6]=q; }
  __syncthreads();
  if (t==0){ stats[0]=ss[0]+ss[1]+ss[2]+ss[3]; stats[1]=qq[0]+qq[1]+qq[2]+qq[3]; }
}

__global__ __launch_bounds__(256) void finalize(
    const float* __restrict__ Z, const float* __restrict__ stats,
    float* __restrict__ out, int row_lo, long long out_off)
{
  int r = row_lo + blockIdx.x;
  int t = threadIdx.x;
  float mean = stats[0] * (1.f/(float)NTOT);
  float var  = stats[1] * (1.f/(float)NTOT) - mean*mean;
  float inv  = rsqrtf(var + 1e-5f);
  float z = (Z[(long long)r*256 + t] - mean) * inv;
  float q = z*z;
  #pragma unroll
  for (int o=32;o;o>>=1) q += __shfl_down(q,o);
  __shared__ float qq[4];
  if ((t&63)==0) qq[t>>6]=q;
  __syncthreads();
  float norm = sqrtf(qq[0]+qq[1]+qq[2]+qq[3]);
  out[out_off + (long long)blockIdx.x*256 + t] = z / (norm + 1e-8f);
}

// ---------------------------------------------------------------- launcher

extern "C" void kernel_launch(void* const* d_in, const int* in_sizes, int n_in,
                              void* d_out, int out_size, void* d_ws, size_t ws_size,
                              hipStream_t stream)
{
  const float* drug_feats    = (const float*)d_in[0];
  const float* target_feats  = (const float*)d_in[1];
  const float* disease_feats = (const float*)d_in[2];
  const float* drug_adjs     = (const float*)d_in[3];
  const float* target_adjs   = (const float*)d_in[4];
  const float* dA_W  = (const float*)d_in[5];
  const float* dA_b  = (const float*)d_in[6];
  const float* dA_g  = (const float*)d_in[7];
  const float* dA_be = (const float*)d_in[8];
  const float* dA_Wr = (const float*)d_in[9];
  const float* dA_br = (const float*)d_in[10];
  const float* tA_W  = (const float*)d_in[11];
  const float* tA_b  = (const float*)d_in[12];
  const float* tA_g  = (const float*)d_in[13];
  const float* tA_be = (const float*)d_in[14];
  const float* tA_Wr = (const float*)d_in[15];
  const float* tA_br = (const float*)d_in[16];
  const float* sA_W  = (const float*)d_in[17];
  const float* sA_b  = (const float*)d_in[18];
  const float* sA_g  = (const float*)d_in[19];
  const float* sA_be = (const float*)d_in[20];
  const float* sA_Wr = (const float*)d_in[21];
  const float* sA_br = (const float*)d_in[22];
  const float* dG_W1 = (const float*)d_in[23];
  const float* dG_W2 = (const float*)d_in[24];
  const float* tG_W1 = (const float*)d_in[25];
  const float* tG_W2 = (const float*)d_in[26];
  const float* dG_a  = (const float*)d_in[27];
  const float* tG_a  = (const float*)d_in[28];

  char* ws = (char*)d_ws;
  size_t off = 0;
  auto alloc = [&](size_t bytes)->void* {
    void* p = ws + off;
    off += (bytes + 255) & ~(size_t)255;
    return p;
  };

  unsigned short* Wc    = (unsigned short*)alloc((size_t)3*1024*1024*2);
  unsigned short* W1Td  = (unsigned short*)alloc((size_t)256*512*2);
  unsigned short* W2Td  = (unsigned short*)alloc((size_t)256*256*2);
  unsigned short* W1Tt  = (unsigned short*)alloc((size_t)256*512*2);
  unsigned short* W2Tt  = (unsigned short*)alloc((size_t)256*256*2);
  unsigned short* xall  = (unsigned short*)alloc((size_t)N_NODES*512*2);
  unsigned short* adjb  = (unsigned short*)alloc((size_t)NROWP*KPAD*2);
  unsigned short* xw1T  = (unsigned short*)alloc((size_t)256*KPAD*2);
  unsigned short* hbuf  = (unsigned short*)alloc((size_t)N_NODES*256*2);
  unsigned short* hw2T  = (unsigned short*)alloc((size_t)256*KPAD*2);
  float* parts = (float*)alloc((size_t)NSPLIT*NTOT*4);   // aliased as C1 (64 MB)
  float* Zf    = (float*)alloc((size_t)NTOT*4);
  float* spart = (float*)alloc((size_t)N_NODES*2*4);
  float* stats = (float*)alloc((size_t)16*4);
  float* C1    = parts;
  float* outp  = (float*)d_out;

  // --- weight casts
  cast_wc<<<3072, 256, 0, stream>>>(dA_W, dA_Wr, tA_W, tA_Wr, sA_W, sA_Wr, Wc);
  transpose_cast<<<512, 256, 0, stream>>>(dG_W1, W1Td, 512, 256);
  transpose_cast<<<256, 256, 0, stream>>>(dG_W2, W2Td, 256, 256);
  transpose_cast<<<512, 256, 0, stream>>>(tG_W1, W1Tt, 512, 256);
  transpose_cast<<<256, 256, 0, stream>>>(tG_W2, W2Tt, 256, 256);

  // --- adapters: C1[g rows][1024] = X_g @ [W_g | Wr_g]^T, f32 A cast in flight
  {
    const float* feats[3] = {drug_feats, target_feats, disease_feats};
    const int gstart[3] = {0, N_DRUG, N_D_T};
    const int gcnt[3]   = {N_DRUG, N_TGT, N_NODES - N_D_T};
    for (int g = 0; g < 3; ++g) {
      int tiles_m = (gcnt[g] + 127) / 128;
      gemmT<128,1><<<tiles_m*4, 512, 0, stream>>>(
          nullptr, feats[g], 0, 1024, 1024,
          Wc + (size_t)g*1024*1024, 1024,
          nullptr, 0,
          gcnt[g], tiles_m, 4, 1, 16,
          0, C1 + (size_t)gstart[g]*1024, 1024, 0, nullptr, 0);
    }
  }
  adapter_fuse<<<N_NODES, 256, 0, stream>>>(C1,
      dA_b, dA_g, dA_be, dA_br,
      tA_b, tA_g, tA_be, tA_br,
      sA_b, sA_g, sA_be, sA_br, xall);

  // --- two GCNs (drug, target), sequential, sharing scratch buffers
  for (int gg = 0; gg < 2; ++gg) {
    const float* adjsrc = gg ? target_adjs : drug_adjs;
    const unsigned short* W1T = gg ? W1Tt : W1Td;
    const unsigned short* W2T = gg ? W2Tt : W2Td;
    const float* aprm = gg ? tG_a : dG_a;

    // xw1T[n][node] = (x_all @ W1)^T   (bf16, zero-padded to KPAD cols)
    gemmT<64,0><<<124, 512, 0, stream>>>(
        xall, nullptr, 0, 512, 512, W1T, 512, nullptr, 0,
        N_NODES, 124, 1, 1, 8,
        1, nullptr, 0, 0, xw1T, KPAD);

    // spmm1: parts = mean(adj planes) @ xw1, fused mean+cast, side-write adjb
    gemmT<64,2><<<123*NSPLIT, 512, 0, stream>>>(
        nullptr, adjsrc, (long long)N_NODES*N_NODES, N_NODES, N_NODES,
        xw1T, KPAD, adjb, KPAD,
        N_NODES, 123, 1, NSPLIT, 124,
        0, parts, 256, (long long)NTOT, nullptr, 0);

    reduce_prelu<<<N_NODES, 256, 0, stream>>>(parts, aprm, hbuf);

    // hw2T[n][node] = (h @ W2)^T
    gemmT<64,0><<<124, 512, 0, stream>>>(
        hbuf, nullptr, 0, 256, 256, W2T, 256, nullptr, 0,
        N_NODES, 124, 1, 1, 4,
        1, nullptr, 0, 0, hw2T, KPAD);

    // spmm2: parts = adjb @ hw2
    gemmT<64,0><<<123*NSPLIT, 512, 0, stream>>>(
        adjb, nullptr, 0, KPAD, KPAD, hw2T, KPAD, nullptr, 0,
        N_NODES, 123, 1, NSPLIT, 124,
        0, parts, 256, (long long)NTOT, nullptr, 0);

    reduce_stats<<<N_NODES, 256, 0, stream>>>(parts, Zf, spart);
    stats_final<<<1, 256, 0, stream>>>(spart, stats);

    if (gg == 0) finalize<<<N_DRUG, 256, 0, stream>>>(Zf, stats, outp, 0, 0LL);
    else         finalize<<<N_TGT, 256, 0, stream>>>(Zf, stats, outp, N_DRUG, (long long)N_DRUG*256);
  }
}

// Round 5
// 1278.689 us; speedup vs baseline: 1.3650x; 1.3650x over previous
//
#include <hip/hip_runtime.h>
#include <hip/hip_bf16.h>
#include <stdint.h>

typedef __attribute__((ext_vector_type(8))) short short8;
typedef __attribute__((ext_vector_type(4))) float f32x4;

#define N_DRUG 708
#define N_TGT  1512
#define N_NODES 7823
#define N_D_T  2220          // 708+1512
#define KPAD   7936          // 124 * 64
#define NROWP  7872          // 123 * 64
#define NTOT   2002688       // 7823*256
#define NSPLIT 8
#define PLANE  61199329LL    // 7823*7823
#define NCHUNK 7649917LL     // ceil(PLANE/8)
#define NPADE  883999LL      // 7823*113 pad-col elements

__device__ __forceinline__ unsigned short f2bf(float f) {
  union { float f; unsigned int i; } v; v.f = f;
  unsigned int r = v.i + 0x7FFF + ((v.i >> 16) & 1);
  return (unsigned short)(r >> 16);
}

__device__ __forceinline__ int4 pack8(const float v[8]) {
  union { int4 i4; unsigned short u[8]; } r;
  #pragma unroll
  for (int j = 0; j < 8; j++) r.u[j] = f2bf(v[j]);
  return r.i4;
}

// ---------------------------------------------------------------- cast kernels

__global__ __launch_bounds__(256) void cast_wc(
    const float* __restrict__ w0, const float* __restrict__ wr0,
    const float* __restrict__ w1, const float* __restrict__ wr1,
    const float* __restrict__ w2, const float* __restrict__ wr2,
    unsigned short* __restrict__ Wc)
{
  long long i4 = ((long long)blockIdx.x*256 + threadIdx.x)*4;   // over 3*1024*1024
  int g  = (int)(i4 >> 20);
  int rr = (int)((i4 >> 10) & 1023);
  int c  = (int)(i4 & 1023);
  const float* src = (g==0) ? (rr<512?w0:wr0) : (g==1) ? (rr<512?w1:wr1) : (rr<512?w2:wr2);
  float4 f = *(const float4*)(src + (long long)(rr & 511)*1024 + c);
  ushort4 v; v.x=f2bf(f.x); v.y=f2bf(f.y); v.z=f2bf(f.z); v.w=f2bf(f.w);
  *(ushort4*)&Wc[i4] = v;
}

__global__ __launch_bounds__(256) void transpose_cast(
    const float* __restrict__ src, unsigned short* __restrict__ dst, int R, int C)
{
  int i = blockIdx.x*256 + threadIdx.x;
  if (i >= R*C) return;
  int r = i / C, c = i - r*C;
  dst[c*R + r] = f2bf(src[i]);
}

// mean of two f32 planes -> bf16 padded [NROWP][KPAD], flat-aligned streaming reads.
__global__ __launch_bounds__(256) void mean_cast(
    const float* __restrict__ adj2, unsigned short* __restrict__ dst)
{
  long long stride = (long long)gridDim.x * 256;
  long long t0 = (long long)blockIdx.x*256 + threadIdx.x;
  const float* p1 = adj2 + PLANE;

  for (long long c = t0; c < NCHUNK; c += stride) {
    long long f = c*8;
    int n = (f + 8 <= PLANE) ? 8 : (int)(PLANE - f);
    float v[8];
    if (n == 8) {
      float4 a0 = *(const float4*)(adj2 + f);
      float4 a1 = *(const float4*)(adj2 + f + 4);
      float4 b0 = *(const float4*)(p1 + f);
      float4 b1 = *(const float4*)(p1 + f + 4);
      v[0]=0.5f*(a0.x+b0.x); v[1]=0.5f*(a0.y+b0.y);
      v[2]=0.5f*(a0.z+b0.z); v[3]=0.5f*(a0.w+b0.w);
      v[4]=0.5f*(a1.x+b1.x); v[5]=0.5f*(a1.y+b1.y);
      v[6]=0.5f*(a1.z+b1.z); v[7]=0.5f*(a1.w+b1.w);
    } else {
      #pragma unroll
      for (int j=0;j<8;j++) v[j] = (j<n) ? 0.5f*(adj2[f+j]+p1[f+j]) : 0.f;
    }
    int row = (int)(f / 7823LL);
    int col = (int)(f - (long long)row*7823LL);
    if (n == 8 && col + 8 <= 7823) {
      unsigned short* d = dst + (long long)row*KPAD + col;
      #pragma unroll
      for (int j=0;j<8;j++) d[j] = f2bf(v[j]);
    } else {
      #pragma unroll
      for (int j=0;j<8;j++) {
        if (j < n) {
          long long ff = f + j;
          int r2 = (int)(ff / 7823LL);
          int c2 = (int)(ff - (long long)r2*7823LL);
          dst[(long long)r2*KPAD + c2] = f2bf(v[j]);
        }
      }
    }
  }
  // zero pad columns 7823..7935 of each real row
  for (long long i = t0; i < NPADE; i += stride) {
    int r = (int)(i / 113LL);
    int c2 = 7823 + (int)(i - (long long)r*113LL);
    dst[(long long)r*KPAD + c2] = 0;
  }
}

// ---------------------------------------------------------------- templated GEMM
// C[m][n] = sum_k A[m][k] * BT[n][k].  BM x 256 tile, BK=64, 512 thr, 8 waves (2x4),
// XOR-swizzled LDS, register prefetch of next K-tile.
// AMODE 0: A bf16 (Ab, lda) ; AMODE 1: A f32 cast-in-flight (Af, lda)
// mode 0: f32 row-major store to Cf + ks*part_stride (rows < m_cnt)
// mode 1: bf16 transposed store CT[n][m], zero-fill m >= m_cnt

#define BN 256
#define BK 64

template<int BM_, int AMODE>
__global__ __launch_bounds__(512, 4) void gemmT(
    const unsigned short* __restrict__ Ab, const float* __restrict__ Af,
    int lda,
    const unsigned short* __restrict__ BT, int ldb,
    int m_cnt, int tiles_m, int tiles_n, int ksplit, int ktiles,
    int mode, float* __restrict__ Cf, int ldc, long long part_stride,
    unsigned short* __restrict__ CT, int ldct)
{
  constexpr int ACH = BM_/64;      // A chunks per thread
  constexpr int MF  = BM_/32;      // m fragments per wave
  __shared__ __align__(16) unsigned short As[BM_*BK];
  __shared__ __align__(16) unsigned short Bs[BN*BK];

  int bid = blockIdx.x;
  int tn = bid % tiles_n;
  int tm = (bid / tiles_n) % tiles_m;
  int ks = bid / (tiles_n * tiles_m);

  int m0 = tm*BM_, n0 = tn*BN;
  int ktper = (ktiles + ksplit - 1) / ksplit;
  int kt0 = ks*ktper;
  int kt1 = min(kt0 + ktper, ktiles);

  int tid = threadIdx.x;
  int lane = tid & 63, w = tid >> 6;
  int wm = (w >> 2)*(BM_/2), wn = (w & 3)*64;

  f32x4 acc[MF][4] = {};

  int arow[ACH], aslot[ACH], brow[4], bslot[4];
  #pragma unroll
  for (int i=0;i<ACH;i++){ int c = i*512 + tid; arow[i] = c>>3; aslot[i] = c&7; }
  #pragma unroll
  for (int i=0;i<4;i++){ int c = i*512 + tid; brow[i] = c>>3; bslot[i] = c&7; }

  int4 ra[ACH], rb[4];

  auto loadAB = [&](int kt){
    #pragma unroll
    for (int i=0;i<ACH;i++){
      int gr = m0 + arow[i]; if (gr > m_cnt-1) gr = m_cnt-1;
      int cb = kt*BK + aslot[i]*8;
      if (AMODE == 0) {
        ra[i] = *(const int4*)(Ab + (long long)gr*lda + cb);
      } else {
        const float* p = Af + (long long)gr*lda + cb;
        float4 f0 = *(const float4*)p;
        float4 f1 = *(const float4*)(p+4);
        float v[8] = {f0.x,f0.y,f0.z,f0.w,f1.x,f1.y,f1.z,f1.w};
        ra[i] = pack8(v);
      }
    }
    #pragma unroll
    for (int i=0;i<4;i++){
      rb[i] = *(const int4*)(BT + (long long)(n0 + brow[i])*ldb + kt*BK + bslot[i]*8);
    }
  };
  auto storeAB = [&](){
    #pragma unroll
    for (int i=0;i<ACH;i++)
      *(int4*)(As + arow[i]*BK + (aslot[i]^(arow[i]&7))*8) = ra[i];
    #pragma unroll
    for (int i=0;i<4;i++)
      *(int4*)(Bs + brow[i]*BK + (bslot[i]^(brow[i]&7))*8) = rb[i];
  };

  loadAB(kt0);

  for (int kt = kt0; kt < kt1; ++kt) {
    __syncthreads();
    storeAB();
    __syncthreads();
    if (kt+1 < kt1) loadAB(kt+1);
    #pragma unroll
    for (int kk=0; kk<2; ++kk) {
      short8 av[MF], bv[4];
      #pragma unroll
      for (int x=0;x<MF;x++){
        int row = wm + x*16 + (lane&15);
        int slot = kk*4 + (lane>>4);
        av[x] = *(const short8*)&As[row*BK + (slot^(row&7))*8];
      }
      #pragma unroll
      for (int x=0;x<4;x++){
        int row = wn + x*16 + (lane&15);
        int slot = kk*4 + (lane>>4);
        bv[x] = *(const short8*)&Bs[row*BK + (slot^(row&7))*8];
      }
      #pragma unroll
      for (int mf=0; mf<MF; ++mf)
        #pragma unroll
        for (int nf=0; nf<4; ++nf)
          acc[mf][nf] = __builtin_amdgcn_mfma_f32_16x16x32_bf16(av[mf], bv[nf], acc[mf][nf], 0, 0, 0);
    }
  }

  if (mode == 0) {
    float* C = Cf + (long long)ks*part_stride;
    #pragma unroll
    for (int mf=0; mf<MF; ++mf) {
      int mb = m0 + wm + mf*16 + ((lane>>4)<<2);
      #pragma unroll
      for (int i=0;i<4;i++){
        int m = mb + i;
        if (m < m_cnt) {
          #pragma unroll
          for (int nf=0; nf<4; ++nf) {
            int n = n0 + wn + nf*16 + (lane&15);
            C[(long long)m*ldc + n] = acc[mf][nf][i];
          }
        }
      }
    }
  } else {
    #pragma unroll
    for (int nf=0; nf<4; ++nf) {
      int n = n0 + wn + nf*16 + (lane&15);
      #pragma unroll
      for (int mf=0; mf<MF; ++mf) {
        int mb = m0 + wm + mf*16 + ((lane>>4)<<2);
        ushort4 v;
        v.x = (mb+0 < m_cnt) ? f2bf(acc[mf][nf][0]) : (unsigned short)0;
        v.y = (mb+1 < m_cnt) ? f2bf(acc[mf][nf][1]) : (unsigned short)0;
        v.z = (mb+2 < m_cnt) ? f2bf(acc[mf][nf][2]) : (unsigned short)0;
        v.w = (mb+3 < m_cnt) ? f2bf(acc[mf][nf][3]) : (unsigned short)0;
        *(ushort4*)&CT[(long long)n*ldct + mb] = v;
      }
    }
  }
}

// ---------------------------------------------------------------- fused epilogues

__global__ __launch_bounds__(256) void adapter_fuse(
    const float* __restrict__ C1,
    const float* __restrict__ b0, const float* __restrict__ g0, const float* __restrict__ be0, const float* __restrict__ br0,
    const float* __restrict__ b1, const float* __restrict__ g1, const float* __restrict__ be1, const float* __restrict__ br1,
    const float* __restrict__ b2, const float* __restrict__ g2, const float* __restrict__ be2, const float* __restrict__ br2,
    unsigned short* __restrict__ xall)
{
  int r = blockIdx.x;
  const float *b, *g, *be, *br;
  if (r < N_DRUG)     { b=b0; g=g0; be=be0; br=br0; }
  else if (r < N_D_T) { b=b1; g=g1; be=be1; br=br1; }
  else                { b=b2; g=g2; be=be2; br=br2; }
  int t = threadIdx.x;
  const float* row = C1 + (long long)r*1024;
  float ya = row[t]       + b[t];
  float yb = row[t + 256] + b[t + 256];
  float s = ya + yb, q = ya*ya + yb*yb;
  #pragma unroll
  for (int o=32;o;o>>=1){ s += __shfl_down(s,o); q += __shfl_down(q,o); }
  __shared__ float ss[4], qq[4];
  if ((t & 63) == 0) { ss[t>>6]=s; qq[t>>6]=q; }
  __syncthreads();
  float S = ss[0]+ss[1]+ss[2]+ss[3];
  float Q = qq[0]+qq[1]+qq[2]+qq[3];
  float mean = S * (1.f/512.f);
  float var  = Q * (1.f/512.f) - mean*mean;
  float inv  = rsqrtf(var + 1e-5f);
  float za = fmaxf((ya-mean)*inv*g[t]     + be[t],     0.f);
  float zb = fmaxf((yb-mean)*inv*g[t+256] + be[t+256], 0.f);
  float ha = za + row[512 + t] + br[t];
  float hb = zb + row[768 + t] + br[t + 256];
  ha = (ha > 0.f) ? ha : (expf(ha) - 1.f);
  hb = (hb > 0.f) ? hb : (expf(hb) - 1.f);
  xall[(long long)r*512 + t]       = f2bf(ha);
  xall[(long long)r*512 + t + 256] = f2bf(hb);
}

__global__ __launch_bounds__(256) void reduce_prelu(
    const float* __restrict__ parts, const float* __restrict__ aP, unsigned short* __restrict__ h)
{
  long long i = (long long)blockIdx.x*256 + threadIdx.x;
  float s = 0.f;
  #pragma unroll
  for (int p=0;p<NSPLIT;p++) s += parts[(long long)p*NTOT + i];
  float a = aP[0];
  h[i] = f2bf(s >= 0.f ? s : a*s);
}

__global__ __launch_bounds__(256) void reduce_stats(
    const float* __restrict__ parts, float* __restrict__ Z, float* __restrict__ sp)
{
  long long i = (long long)blockIdx.x*256 + threadIdx.x;
  float s = 0.f;
  #pragma unroll
  for (int p=0;p<NSPLIT;p++) s += parts[(long long)p*NTOT + i];
  Z[i] = s;
  float a = s, q = s*s;
  #pragma unroll
  for (int o=32;o;o>>=1){ a += __shfl_down(a,o); q += __shfl_down(q,o); }
  __shared__ float ss[4], qq[4];
  int t = threadIdx.x;
  if ((t&63)==0){ ss[t>>6]=a; qq[t>>6]=q; }
  __syncthreads();
  if (t==0) {
    sp[2*blockIdx.x]   = ss[0]+ss[1]+ss[2]+ss[3];
    sp[2*blockIdx.x+1] = qq[0]+qq[1]+qq[2]+qq[3];
  }
}

__global__ __launch_bounds__(256) void stats_final(
    const float* __restrict__ sp, float* __restrict__ stats)
{
  int t = threadIdx.x;
  float s = 0.f, q = 0.f;
  for (int i=t; i<N_NODES; i+=256){ s += sp[2*i]; q += sp[2*i+1]; }
  #pragma unroll
  for (int o=32;o;o>>=1){ s += __shfl_down(s,o); q += __shfl_down(q,o); }
  __shared__ float ss[4], qq[4];
  if ((t&63)==0){ ss[t>>6]=s; qq[t>>6]=q; }
  __syncthreads();
  if (t==0){ stats[0]=ss[0]+ss[1]+ss[2]+ss[3]; stats[1]=qq[0]+qq[1]+qq[2]+qq[3]; }
}

__global__ __launch_bounds__(256) void finalize(
    const float* __restrict__ Z, const float* __restrict__ stats,
    float* __restrict__ out, int row_lo, long long out_off)
{
  int r = row_lo + blockIdx.x;
  int t = threadIdx.x;
  float mean = stats[0] * (1.f/(float)NTOT);
  float var  = stats[1] * (1.f/(float)NTOT) - mean*mean;
  float inv  = rsqrtf(var + 1e-5f);
  float z = (Z[(long long)r*256 + t] - mean) * inv;
  float q = z*z;
  #pragma unroll
  for (int o=32;o;o>>=1) q += __shfl_down(q,o);
  __shared__ float qq[4];
  if ((t&63)==0) qq[t>>6]=q;
  __syncthreads();
  float norm = sqrtf(qq[0]+qq[1]+qq[2]+qq[3]);
  out[out_off + (long long)blockIdx.x*256 + t] = z / (norm + 1e-8f);
}

// ---------------------------------------------------------------- launcher

extern "C" void kernel_launch(void* const* d_in, const int* in_sizes, int n_in,
                              void* d_out, int out_size, void* d_ws, size_t ws_size,
                              hipStream_t stream)
{
  const float* drug_feats    = (const float*)d_in[0];
  const float* target_feats  = (const float*)d_in[1];
  const float* disease_feats = (const float*)d_in[2];
  const float* drug_adjs     = (const float*)d_in[3];
  const float* target_adjs   = (const float*)d_in[4];
  const float* dA_W  = (const float*)d_in[5];
  const float* dA_b  = (const float*)d_in[6];
  const float* dA_g  = (const float*)d_in[7];
  const float* dA_be = (const float*)d_in[8];
  const float* dA_Wr = (const float*)d_in[9];
  const float* dA_br = (const float*)d_in[10];
  const float* tA_W  = (const float*)d_in[11];
  const float* tA_b  = (const float*)d_in[12];
  const float* tA_g  = (const float*)d_in[13];
  const float* tA_be = (const float*)d_in[14];
  const float* tA_Wr = (const float*)d_in[15];
  const float* tA_br = (const float*)d_in[16];
  const float* sA_W  = (const float*)d_in[17];
  const float* sA_b  = (const float*)d_in[18];
  const float* sA_g  = (const float*)d_in[19];
  const float* sA_be = (const float*)d_in[20];
  const float* sA_Wr = (const float*)d_in[21];
  const float* sA_br = (const float*)d_in[22];
  const float* dG_W1 = (const float*)d_in[23];
  const float* dG_W2 = (const float*)d_in[24];
  const float* tG_W1 = (const float*)d_in[25];
  const float* tG_W2 = (const float*)d_in[26];
  const float* dG_a  = (const float*)d_in[27];
  const float* tG_a  = (const float*)d_in[28];

  char* ws = (char*)d_ws;
  size_t off = 0;
  auto alloc = [&](size_t bytes)->void* {
    void* p = ws + off;
    off += (bytes + 255) & ~(size_t)255;
    return p;
  };

  unsigned short* Wc    = (unsigned short*)alloc((size_t)3*1024*1024*2);
  unsigned short* W1Td  = (unsigned short*)alloc((size_t)256*512*2);
  unsigned short* W2Td  = (unsigned short*)alloc((size_t)256*256*2);
  unsigned short* W1Tt  = (unsigned short*)alloc((size_t)256*512*2);
  unsigned short* W2Tt  = (unsigned short*)alloc((size_t)256*256*2);
  unsigned short* xall  = (unsigned short*)alloc((size_t)N_NODES*512*2);
  unsigned short* adjb  = (unsigned short*)alloc((size_t)NROWP*KPAD*2);
  unsigned short* xw1T  = (unsigned short*)alloc((size_t)256*KPAD*2);
  unsigned short* hbuf  = (unsigned short*)alloc((size_t)N_NODES*256*2);
  unsigned short* hw2T  = (unsigned short*)alloc((size_t)256*KPAD*2);
  float* parts = (float*)alloc((size_t)NSPLIT*NTOT*4);   // aliased as C1 (64 MB)
  float* Zf    = (float*)alloc((size_t)NTOT*4);
  float* spart = (float*)alloc((size_t)N_NODES*2*4);
  float* stats = (float*)alloc((size_t)16*4);
  float* C1    = parts;
  float* outp  = (float*)d_out;

  // --- weight casts
  cast_wc<<<3072, 256, 0, stream>>>(dA_W, dA_Wr, tA_W, tA_Wr, sA_W, sA_Wr, Wc);
  transpose_cast<<<512, 256, 0, stream>>>(dG_W1, W1Td, 512, 256);
  transpose_cast<<<256, 256, 0, stream>>>(dG_W2, W2Td, 256, 256);
  transpose_cast<<<512, 256, 0, stream>>>(tG_W1, W1Tt, 512, 256);
  transpose_cast<<<256, 256, 0, stream>>>(tG_W2, W2Tt, 256, 256);

  // --- adapters: C1[g rows][1024] = X_g @ [W_g | Wr_g]^T, f32 A cast in flight
  {
    const float* feats[3] = {drug_feats, target_feats, disease_feats};
    const int gstart[3] = {0, N_DRUG, N_D_T};
    const int gcnt[3]   = {N_DRUG, N_TGT, N_NODES - N_D_T};
    for (int g = 0; g < 3; ++g) {
      int tiles_m = (gcnt[g] + 63) / 64;
      gemmT<64,1><<<tiles_m*4, 512, 0, stream>>>(
          nullptr, feats[g], 1024,
          Wc + (size_t)g*1024*1024, 1024,
          gcnt[g], tiles_m, 4, 1, 16,
          0, C1 + (size_t)gstart[g]*1024, 1024, 0, nullptr, 0);
    }
  }
  adapter_fuse<<<N_NODES, 256, 0, stream>>>(C1,
      dA_b, dA_g, dA_be, dA_br,
      tA_b, tA_g, tA_be, tA_br,
      sA_b, sA_g, sA_be, sA_br, xall);

  // --- two GCNs (drug, target), sequential, sharing scratch buffers
  for (int gg = 0; gg < 2; ++gg) {
    const float* adjsrc = gg ? target_adjs : drug_adjs;
    const unsigned short* W1T = gg ? W1Tt : W1Td;
    const unsigned short* W2T = gg ? W2Tt : W2Td;
    const float* aprm = gg ? tG_a : dG_a;

    // aligned streaming mean+cast: adjb[7872][7936] bf16, pad cols zeroed
    mean_cast<<<2048, 256, 0, stream>>>(adjsrc, adjb);

    // xw1T[n][node] = (x_all @ W1)^T   (bf16, zero-padded to KPAD cols)
    gemmT<64,0><<<124, 512, 0, stream>>>(
        xall, nullptr, 512, W1T, 512,
        N_NODES, 124, 1, 1, 8,
        1, nullptr, 0, 0, xw1T, KPAD);

    // spmm1: parts = adjb @ xw1  (split-K 8)
    gemmT<128,0><<<62*NSPLIT, 512, 0, stream>>>(
        adjb, nullptr, KPAD, xw1T, KPAD,
        N_NODES, 62, 1, NSPLIT, 124,
        0, parts, 256, (long long)NTOT, nullptr, 0);

    reduce_prelu<<<N_NODES, 256, 0, stream>>>(parts, aprm, hbuf);

    // hw2T[n][node] = (h @ W2)^T
    gemmT<64,0><<<124, 512, 0, stream>>>(
        hbuf, nullptr, 256, W2T, 256,
        N_NODES, 124, 1, 1, 4,
        1, nullptr, 0, 0, hw2T, KPAD);

    // spmm2: parts = adjb @ hw2  (split-K 8)
    gemmT<128,0><<<62*NSPLIT, 512, 0, stream>>>(
        adjb, nullptr, KPAD, hw2T, KPAD,
        N_NODES, 62, 1, NSPLIT, 124,
        0, parts, 256, (long long)NTOT, nullptr, 0);

    reduce_stats<<<N_NODES, 256, 0, stream>>>(parts, Zf, spart);
    stats_final<<<1, 256, 0, stream>>>(spart, stats);

    if (gg == 0) finalize<<<N_DRUG, 256, 0, stream>>>(Zf, stats, outp, 0, 0LL);
    else         finalize<<<N_TGT, 256, 0, stream>>>(Zf, stats, outp, N_DRUG, (long long)N_DRUG*256);
  }
}